// Round 1
// baseline (355.524 us; speedup 1.0000x reference)
//
#include <hip/hip_runtime.h>

// visco11: 8-wave chain groups (was 4). 512-thread blocks, 2 blocks/CU ->
// 4 waves/SIMD (was 2). Each wave owns 64 hidden rows (4 L1 tiles, 2 L2
// k-chunks). A2 fragments + w6 correction vectors live in LDS (re-read per
// phase, early-issued, latency hidden under volley) to fit the 128-VGPR cap
// that launch_bounds(512,4) imposes. X k-slots 8..31 are garbage-but-finite
// (A1 is zeroed there), so the per-phase cndmasks are gone. Stress lazy-sum
// alternates waves 6/7 to halve barrier skew.

typedef __attribute__((ext_vector_type(8))) short s8v;   // 8 x bf16 (4 VGPR)
typedef __attribute__((ext_vector_type(4))) float f4v;   // 16x16 MFMA acc
typedef __attribute__((ext_vector_type(2))) float f2v;

#define NB 8192
#define NT 128
#define DTC 0.01f

union S8 { s8v v; int i[4]; };
union F4 { f4v v; float f[4]; };

static __device__ __forceinline__ int cvtpk(float lo, float hi) {
    int r;
    asm("v_cvt_pk_bf16_f32 %0, %1, %2" : "=v"(r) : "v"(lo), "v"(hi));
    return r;
}

static __device__ __forceinline__ f4v mfma16(s8v a, s8v b, f4v c) {
    return __builtin_amdgcn_mfma_f32_16x16x32_bf16(a, b, c, 0, 0, 0);
}

// LDS-only barrier: order LDS ops (lgkmcnt) + rendezvous. No vmcnt drain —
// global prefetch loads / output stores stay in flight across it.
// Race-safety: every post-barrier LDS READ is drained by the reader's own
// NEXT bar_lds (lgkmcnt(0)) BEFORE any wave can pass that barrier and
// re-write the buffer -> single-buffering is race-free.
static __device__ __forceinline__ void bar_lds() {
    asm volatile("s_waitcnt lgkmcnt(0)\n\ts_barrier" ::: "memory");
}

// Layer-1 e-part volley: 4 tiles of 16 hidden rows (wave owns 64 rows).
static __device__ __forceinline__ void volley4(const S8* A1m, s8v X, F4* t) {
    const f4v z = {0.f, 0.f, 0.f, 0.f};
#pragma unroll
    for (int tau = 0; tau < 4; ++tau) t[tau].v = mfma16(A1m[tau].v, X, z);
}

// x6-linearity correction: t[tau][i] += w6[H(tau,4g+i)] * x6
static __device__ __forceinline__ void corr4(F4* t, const f4v* w6t, float x6) {
    const f4v sp = {x6, x6, x6, x6};
#pragma unroll
    for (int tau = 0; tau < 4; ++tau)
        t[tau].v = __builtin_elementwise_fma(w6t[tau], sp, t[tau].v);
}

// relu + bf16 pack (zero-shuffle slot map) + 2 INDEPENDENT k-chunk MFMAs.
static __device__ __forceinline__ f4v packL2_2(s8v a20, s8v a21, const F4* t) {
    const f4v z = {0.f, 0.f, 0.f, 0.f};
    S8 B0, B1;
    {
        f4v r0 = __builtin_elementwise_max(t[0].v, z);
        f4v r1 = __builtin_elementwise_max(t[1].v, z);
        B0.i[0] = cvtpk(r0.x, r0.y);
        B0.i[1] = cvtpk(r0.z, r0.w);
        B0.i[2] = cvtpk(r1.x, r1.y);
        B0.i[3] = cvtpk(r1.z, r1.w);
    }
    {
        f4v r2 = __builtin_elementwise_max(t[2].v, z);
        f4v r3 = __builtin_elementwise_max(t[3].v, z);
        B1.i[0] = cvtpk(r2.x, r2.y);
        B1.i[1] = cvtpk(r2.z, r2.w);
        B1.i[2] = cvtpk(r3.x, r3.y);
        B1.i[3] = cvtpk(r3.z, r3.w);
    }
    f4v a = mfma16(a20, B0.v, z);
    f4v b = mfma16(a21, B1.v, z);
    return a + b;
}

__global__ __launch_bounds__(512, 4)
void visco11(const float* __restrict__ e,     // [B,T,6]
             const float* __restrict__ ed,    // [B,T,6]
             const float* __restrict__ We1,   // [512,7]
             const float* __restrict__ be1,   // [512]
             const float* __restrict__ we2,   // [512]
             const float* __restrict__ Wd1,   // [512,7]
             const float* __restrict__ bd1,   // [512]
             const float* __restrict__ wd2,   // [512]
             float* __restrict__ out_s,       // [B,T,6]
             float* __restrict__ out_xi)      // [B,T]
{
    // ONE 8-wave chain-group per block (16 samples); 2 blocks/CU.
    __shared__ F4 redS[8][32];                          // stress partials
    __shared__ __align__(16) float dredD[16][12];       // comp-6 partials [s][w] (pad 12: 2-way banks)
    __shared__ __align__(16) float dredE[16][12];
    __shared__ f4v w6lds[2][128];                       // [p][H/4]: W1[:,6] (D negated)
    __shared__ s8v a2lds[2][8][2][64];                  // [p][w][chunk][lane]

    const int tid = threadIdx.x;
    const int lane = tid & 63;
    const int w = tid >> 6;          // 0..7
    const int s = lane & 15;         // sample column
    const int g = lane >> 4;         // 0..3 (k-group / row-group)
    const bool g0 = (g == 0);
    const int K67 = 0x3F800000;      // cvtpk(0.0f, 1.0f): slot6=0, slot7=1

    // ---------- static weights: wave owns hidden rows w*64..+63 ----------
    // slot map: H(tau, r) = w*64 + tau*16 + r; layer2 k-slot (c,g,i) ->
    // H(2c + (i>>2), 4g + (i&3))  => layer1 D regs ARE layer2 B (zero shuffle).
    S8 A1[2][4];
    {
        const float* W1s[2] = {We1, Wd1};
        const float* b1s[2] = {be1, bd1};
        const float* w2s[2] = {we2, wd2};
#pragma unroll
        for (int p = 0; p < 2; ++p) {
            const float* W1 = W1s[p];
            const float* b1 = b1s[p];
            const float* w2 = w2s[p];
            const float sgn = (p == 1) ? -1.0f : 1.0f;   // fold -d into weights
            {
                const int H = w * 64 + lane;             // each wave fills its 64 rows
                ((float*)&w6lds[p][0])[H] = sgn * W1[H * 7 + 6];
            }
#pragma unroll
            for (int tau = 0; tau < 4; ++tau) {
                S8 f; f.i[0] = f.i[1] = f.i[2] = f.i[3] = 0;
                if (g0) {
                    const int H = w * 64 + tau * 16 + s;
                    const float* row = W1 + H * 7;
                    f.i[0] = cvtpk(row[0], row[1]);
                    f.i[1] = cvtpk(row[2], row[3]);
                    f.i[2] = cvtpk(row[4], row[5]);
                    f.i[3] = cvtpk(row[6], b1[H]);   // bias via X slot7 = 1.0
                }
                A1[p][tau] = f;
            }
#pragma unroll
            for (int c = 0; c < 2; ++c) {
                S8 f;
#pragma unroll
                for (int ii = 0; ii < 4; ++ii) {
                    const int i0 = 2 * ii, i1 = 2 * ii + 1;
                    const int H0 = w * 64 + (2 * c + (i0 >> 2)) * 16 + 4 * g + (i0 & 3);
                    const int H1 = w * 64 + (2 * c + (i1 >> 2)) * 16 + 4 * g + (i1 & 3);
                    const float v0 = (s < 7) ? W1[H0 * 7 + s] * 2.0f * w2[H0] : 0.f;
                    const float v1 = (s < 7) ? W1[H1 * 7 + s] * 2.0f * w2[H1] : 0.f;
                    f.i[ii] = cvtpk(v0, v1);
                }
                a2lds[p][w][c][lane] = f.v;
            }
        }
    }
    bar_lds();   // LDS tables visible to all waves

    // ---------- recurrence ----------
    const size_t sm = (size_t)blockIdx.x * 16 + s;
    const f2v* pE = (const f2v*)(e + sm * 768);
    const f2v* pD = (const f2v*)(ed + sm * 768);
    float* sB = out_s + sm * 768;
    float* xB = out_xi + sm * NT;

    // initial loads: e[0], ed[0] (now), e[1] / ed[1] into rolling buffers
    f2v p0 = pE[0], p1 = pE[1], p2 = pE[2];
    f2v q0 = pD[0], q1 = pD[1], q2 = pD[2];
    f2v eR0 = pE[3], eR1 = pE[4], eR2 = pE[5];     // e[1]
    f2v dR0 = pD[3], dR1 = pD[4], dR2 = pD[5];     // ed[1]

    F4 t[4];
    S8 XD, XE;
    F4 accD, accE;
    XD.i[3] = K67;
    XE.i[3] = K67;

    // ---- prologue: E eval at (e[0], xi = 0); no corr needed ----
    XE.i[0] = cvtpk(p0.x, p0.y);
    XE.i[1] = cvtpk(p1.x, p1.y);
    XE.i[2] = cvtpk(p2.x, p2.y);
    volley4(A1[0], XE.v, t);
    {
        S8 a20, a21;
        a20.v = a2lds[0][w][0][lane];
        a21.v = a2lds[0][w][1][lane];
        accE.v = packL2_2(a20.v, a21.v, t);
    }
    if (g == 1) dredE[s][w] = accE.f[2];           // d-partial
    // pack XD(0) from ed[0]
    XD.i[0] = cvtpk(q0.x, q0.y);
    XD.i[1] = cvtpk(q1.x, q1.y);
    XD.i[2] = cvtpk(q2.x, q2.y);
    float xi = 0.f;
    if (w == 1 && g0) xB[0] = 0.f;

#pragma unroll 1
    for (int it = 0; it < NT - 1; ++it) {
        // ===== phase D(it): dissipation at (ed[it], -d_it) =====
        bar_lds();                               // syncs dredE writes
        F4 dpA, dpB;
        dpA.v = *(const f4v*)&dredE[s][0];       // 2 ds_reads (hide under volley)
        dpB.v = *(const f4v*)&dredE[s][4];
        f4v w6t[4];
#pragma unroll
        for (int tau = 0; tau < 4; ++tau) w6t[tau] = w6lds[1][w * 16 + tau * 4 + g];
        S8 a20, a21;
        a20.v = a2lds[1][w][0][lane];
        a21.v = a2lds[1][w][1][lane];
        volley4(A1[1], XD.v, t);                 // e-part, independent of d
        F4 dsm; dsm.v = dpA.v + dpB.v;
        const float d = (dsm.f[0] + dsm.f[1]) + (dsm.f[2] + dsm.f[3]);
        corr4(t, w6t, d);                        // w6lds[1] pre-negated => -d
        accD.v = packL2_2(a20.v, a21.v, t);
        F4 sp; sp.v = accE.v - accD.v;           // stress[it] partial
        if (lane < 32) redS[w][lane].v = sp.v;
        if (g == 1) dredD[s][w] = accD.f[2];     // kin partial
        // off-chain: pack XE(it) <- e[it+1]; issue load e[it+2]
        XE.i[0] = cvtpk(eR0.x, eR0.y);
        XE.i[1] = cvtpk(eR1.x, eR1.y);
        XE.i[2] = cvtpk(eR2.x, eR2.y);
        {
            const int tn = (it + 2 < NT) ? it + 2 : NT - 1;
            eR0 = pE[3 * tn]; eR1 = pE[3 * tn + 1]; eR2 = pE[3 * tn + 2];
        }

        // ===== phase E(it): energy at (e[it+1], xi_{it+1}) =====
        bar_lds();                               // syncs dredD + redS writes
        F4 dqA, dqB;
        dqA.v = *(const f4v*)&dredD[s][0];
        dqB.v = *(const f4v*)&dredD[s][4];
        f4v w6u[4];
#pragma unroll
        for (int tau = 0; tau < 4; ++tau) w6u[tau] = w6lds[0][w * 16 + tau * 4 + g];
        S8 b20, b21;
        b20.v = a2lds[0][w][0][lane];
        b21.v = a2lds[0][w][1][lane];
        volley4(A1[0], XE.v, t);                 // e-part, independent of xi
        // lazy stress sum + store; alternate waves 6/7 to halve barrier skew
        if (w == 6 + (it & 1)) {
            const int l31 = lane & 31;
            f4v st = ((redS[0][l31].v + redS[1][l31].v) +
                      (redS[2][l31].v + redS[3][l31].v)) +
                     ((redS[4][l31].v + redS[5][l31].v) +
                      (redS[6][l31].v + redS[7][l31].v));
            float* ps = sB + it * 6;
            if (g == 0) {
                ((f2v*)ps)[0] = f2v{st.x, st.y};
                ((f2v*)ps)[1] = f2v{st.z, st.w};
            } else if (g == 1) {
                ((f2v*)ps)[2] = f2v{st.x, st.y};
            }
        }
        F4 dq; dq.v = dqA.v + dqB.v;
        const float kin = (dq.f[0] + dq.f[1]) + (dq.f[2] + dq.f[3]);
        xi = fmaf(DTC, kin, xi);
        if (w == 1 && g0) xB[it + 1] = xi;
        corr4(t, w6u, xi);
        accE.v = packL2_2(b20.v, b21.v, t);
        if (g == 1) dredE[s][w] = accE.f[2];
        // off-chain: pack XD(it+1) <- ed[it+1]; issue load ed[it+2]
        XD.i[0] = cvtpk(dR0.x, dR0.y);
        XD.i[1] = cvtpk(dR1.x, dR1.y);
        XD.i[2] = cvtpk(dR2.x, dR2.y);
        {
            const int tn = (it + 2 < NT) ? it + 2 : NT - 1;
            dR0 = pD[3 * tn]; dR1 = pD[3 * tn + 1]; dR2 = pD[3 * tn + 2];
        }
    }

    // ===== epilogue: stress[127] = s_eq(final E) - s_neq(final D) =====
    bar_lds();   // all waves' in-flight redS reads drained (own lgkm drain)
    F4 spf; spf.v = accE.v - accD.v;
    if (lane < 32) redS[w][lane].v = spf.v;
    bar_lds();
    if (w == 7) {
        const int l31 = lane & 31;
        f4v st = ((redS[0][l31].v + redS[1][l31].v) +
                  (redS[2][l31].v + redS[3][l31].v)) +
                 ((redS[4][l31].v + redS[5][l31].v) +
                  (redS[6][l31].v + redS[7][l31].v));
        float* ps = sB + (NT - 1) * 6;
        if (g == 0) {
            ((f2v*)ps)[0] = f2v{st.x, st.y};
            ((f2v*)ps)[1] = f2v{st.z, st.w};
        } else if (g == 1) {
            ((f2v*)ps)[2] = f2v{st.x, st.y};
        }
    }
}

extern "C" void kernel_launch(void* const* d_in, const int* in_sizes, int n_in,
                              void* d_out, int out_size, void* d_ws, size_t ws_size,
                              hipStream_t stream) {
    const float* e    = (const float*)d_in[0];
    const float* edot = (const float*)d_in[1];
    const float* We1  = (const float*)d_in[2];
    const float* be1  = (const float*)d_in[3];
    const float* we2  = (const float*)d_in[4];
    // d_in[5] = be2 (constant, vanishes in gradient)
    const float* Wd1  = (const float*)d_in[6];
    const float* bd1  = (const float*)d_in[7];
    const float* wd2  = (const float*)d_in[8];
    // d_in[9] = bd2 (unused)

    float* out_stress = (float*)d_out;                         // [B,T,6]
    float* out_xi     = (float*)d_out + (size_t)NB * NT * 6;   // [B,T,1]

    visco11<<<NB / 16, 512, 0, stream>>>(e, edot, We1, be1, we2,
                                         Wd1, bd1, wd2, out_stress, out_xi);
}

// Round 5
// 246.298 us; speedup vs baseline: 1.4435x; 1.4435x over previous
//
#include <hip/hip_runtime.h>

// visco15: verified visco10 + ONE mechanical transform: software-pipeline the
// L1 volleys one phase early. Each phase issues the NEXT phase's 8-MFMA
// volley (register-only inputs: rolling e/ed buffers + static A1), so the
// post-barrier critical path shrinks to ds_read -> sum -> corr -> pack, with
// the hoisted volley + cvtpk X-pack running in the ds_read/rendezvous shadow.
// Second t-register set (tD/tE) costs +32 VGPR (124 -> ~160, cap 256).
// Also: lazy stress-sum alternates waves 2/3 to halve barrier skew.
// ALL masking (g0 ? ... : 0 on X), barrier discipline, weight slot maps, and
// reduce paths are byte-identical to visco10 (three NaN failures R2-R4 all
// shared the removal of X masking — not repeated here).

typedef __attribute__((ext_vector_type(8))) short s8v;   // 8 x bf16 (4 VGPR)
typedef __attribute__((ext_vector_type(4))) float f4v;   // 16x16 MFMA acc
typedef __attribute__((ext_vector_type(2))) float f2v;

#define NB 8192
#define NT 128
#define DTC 0.01f

union S8 { s8v v; int i[4]; };
union F4 { f4v v; float f[4]; };

static __device__ __forceinline__ int cvtpk(float lo, float hi) {
    int r;
    asm("v_cvt_pk_bf16_f32 %0, %1, %2" : "=v"(r) : "v"(lo), "v"(hi));
    return r;
}

static __device__ __forceinline__ f4v mfma16(s8v a, s8v b, f4v c) {
    return __builtin_amdgcn_mfma_f32_16x16x32_bf16(a, b, c, 0, 0, 0);
}

// LDS-only barrier: order LDS ops (lgkmcnt) + rendezvous. No vmcnt drain —
// global prefetch loads / output stores stay in flight across it.
// Race-safety: every post-barrier LDS READ is drained by the reader's own
// NEXT bar_lds (lgkmcnt(0)) BEFORE any wave can pass that barrier and
// re-write the buffer -> single-buffering is race-free.
static __device__ __forceinline__ void bar_lds() {
    asm volatile("s_waitcnt lgkmcnt(0)\n\ts_barrier" ::: "memory");
}

// Layer-1 e-part volley: 8 tiles of 16 hidden rows (wave owns 128 rows).
// X slot6 = 0 (x6 added later on VALU), slot7 = 1.0 (bias).
static __device__ __forceinline__ void volley(const S8* A1m, s8v X, F4* t) {
    const f4v z = {0.f, 0.f, 0.f, 0.f};
#pragma unroll
    for (int tau = 0; tau < 8; ++tau) t[tau].v = mfma16(A1m[tau].v, X, z);
}

// x6-linearity correction: t[tau][i] += w6[H(tau,4g+i)] * x6  (packed f32 FMA)
static __device__ __forceinline__ void corr8(F4* t, const f4v* w6m, float x6) {
    const f4v sp = {x6, x6, x6, x6};
#pragma unroll
    for (int tau = 0; tau < 8; ++tau)
        t[tau].v = __builtin_elementwise_fma(w6m[tau], sp, t[tau].v);
}

// relu (packed max) + bf16 pack (zero-shuffle slot map) + 4 k-chunk MFMAs.
static __device__ __forceinline__ f4v packL2(const S8* A2m, const F4* t) {
    const f4v z = {0.f, 0.f, 0.f, 0.f};
    S8 B[4];
#pragma unroll
    for (int c = 0; c < 4; ++c) {
        f4v r0 = __builtin_elementwise_max(t[2 * c].v, z);
        f4v r1 = __builtin_elementwise_max(t[2 * c + 1].v, z);
        B[c].i[0] = cvtpk(r0.x, r0.y);
        B[c].i[1] = cvtpk(r0.z, r0.w);
        B[c].i[2] = cvtpk(r1.x, r1.y);
        B[c].i[3] = cvtpk(r1.z, r1.w);
    }
    f4v a = mfma16(A2m[0].v, B[0].v, z);
    a = mfma16(A2m[1].v, B[1].v, a);
    f4v b = mfma16(A2m[2].v, B[2].v, z);
    b = mfma16(A2m[3].v, B[3].v, b);
    return a + b;
}

__global__ __launch_bounds__(256, 2)
void visco15(const float* __restrict__ e,     // [B,T,6]
             const float* __restrict__ ed,    // [B,T,6]
             const float* __restrict__ We1,   // [512,7]
             const float* __restrict__ be1,   // [512]
             const float* __restrict__ we2,   // [512]
             const float* __restrict__ Wd1,   // [512,7]
             const float* __restrict__ bd1,   // [512]
             const float* __restrict__ wd2,   // [512]
             float* __restrict__ out_s,       // [B,T,6]
             float* __restrict__ out_xi)      // [B,T]
{
    // ONE 4-wave chain-group per block (16 samples) -> private barrier scope;
    // two independent blocks co-resident per CU overlap their chain latencies.
    __shared__ F4 redS[4][32];           // stress partial-difference
    __shared__ f4v dredD[16], dredE[16]; // comp-6 partials [sample]

    const int tid = threadIdx.x;
    const int lane = tid & 63;
    const int w = tid >> 6;          // 0..3
    const int s = lane & 15;         // sample column
    const int g = lane >> 4;         // 0..3 (k-group / row-group)
    const bool g0 = (g == 0);
    const int K67 = 0x3F800000;      // cvtpk(0.0f, 1.0f): slot6=0, slot7=1

    // ---------- static weight fragments: wave owns hidden rows w*128..+127 ----
    // slot map: H(tau, r) = w*128 + tau*16 + r; layer2 k-slot (c,g,i) ->
    // H(2c + (i>>2), 4g + (i&3))  => layer1 D regs ARE layer2 B (zero shuffle).
    S8 A1[2][8], A2[2][4];
    f4v w6r[2][8];                   // W1[:,6] in C/D layout; MLP-D stored NEGATED
    {
        const float* W1s[2] = {We1, Wd1};
        const float* b1s[2] = {be1, bd1};
        const float* w2s[2] = {we2, wd2};
#pragma unroll
        for (int p = 0; p < 2; ++p) {
            const float* W1 = W1s[p];
            const float* b1 = b1s[p];
            const float* w2 = w2s[p];
            const float sgn = (p == 1) ? -1.0f : 1.0f;   // fold -d into weights
#pragma unroll
            for (int tau = 0; tau < 8; ++tau) {
                S8 f; f.i[0] = f.i[1] = f.i[2] = f.i[3] = 0;
                if (g0) {
                    const int H = w * 128 + tau * 16 + s;
                    const float* row = W1 + H * 7;
                    f.i[0] = cvtpk(row[0], row[1]);
                    f.i[1] = cvtpk(row[2], row[3]);
                    f.i[2] = cvtpk(row[4], row[5]);
                    f.i[3] = cvtpk(row[6], b1[H]);   // bias via X slot7 = 1.0
                }
                A1[p][tau] = f;
                const int Hj = w * 128 + tau * 16 + 4 * g;
                f4v wv;
                wv.x = sgn * W1[(Hj + 0) * 7 + 6];
                wv.y = sgn * W1[(Hj + 1) * 7 + 6];
                wv.z = sgn * W1[(Hj + 2) * 7 + 6];
                wv.w = sgn * W1[(Hj + 3) * 7 + 6];
                w6r[p][tau] = wv;
            }
#pragma unroll
            for (int c = 0; c < 4; ++c) {
                S8 f;
#pragma unroll
                for (int ii = 0; ii < 4; ++ii) {
                    const int i0 = 2 * ii, i1 = 2 * ii + 1;
                    const int H0 = w * 128 + (2 * c + (i0 >> 2)) * 16 + 4 * g + (i0 & 3);
                    const int H1 = w * 128 + (2 * c + (i1 >> 2)) * 16 + 4 * g + (i1 & 3);
                    const float v0 = (s < 7) ? W1[H0 * 7 + s] * 2.0f * w2[H0] : 0.f;
                    const float v1 = (s < 7) ? W1[H1 * 7 + s] * 2.0f * w2[H1] : 0.f;
                    f.i[ii] = cvtpk(v0, v1);
                }
                A2[p][c] = f;
            }
        }
    }

    // ---------- recurrence ----------
    const size_t sm = (size_t)blockIdx.x * 16 + s;
    const f2v* pE = (const f2v*)(e + sm * 768);
    const f2v* pD = (const f2v*)(ed + sm * 768);
    float* sB = out_s + sm * 768;
    float* xB = out_xi + sm * NT;

    // initial loads: e[0], ed[0] (now), e[1] / ed[1] into rolling buffers
    f2v p0 = pE[0], p1 = pE[1], p2 = pE[2];
    f2v q0 = pD[0], q1 = pD[1], q2 = pD[2];
    f2v eR0 = pE[3], eR1 = pE[4], eR2 = pE[5];     // e[1]
    f2v dR0 = pD[3], dR1 = pD[4], dR2 = pD[5];     // ed[1]

    F4 tD[8], tE[8];                 // pipelined volley results (D / E phases)
    S8 XD, XE;
    F4 accD, accE;

    // ---- prologue: E eval at (e[0], xi = 0); no corr needed ----
    XE.i[0] = g0 ? cvtpk(p0.x, p0.y) : 0;
    XE.i[1] = g0 ? cvtpk(p1.x, p1.y) : 0;
    XE.i[2] = g0 ? cvtpk(p2.x, p2.y) : 0;
    XE.i[3] = g0 ? K67 : 0;
    volley(A1[0], XE.v, tE);
    accE.v = packL2(A2[0], tE);
    if (g == 1) ((float*)&dredE[s])[w] = accE.f[2];   // d-partial
    // pack XD(0) from ed[0]; pre-issue the D(0) volley (pipeline prime)
    XD.i[0] = g0 ? cvtpk(q0.x, q0.y) : 0;
    XD.i[1] = g0 ? cvtpk(q1.x, q1.y) : 0;
    XD.i[2] = g0 ? cvtpk(q2.x, q2.y) : 0;
    XD.i[3] = g0 ? K67 : 0;
    volley(A1[1], XD.v, tD);
    float xi = 0.f;
    if (w == 1 && g0) xB[0] = 0.f;

#pragma unroll 1
    for (int it = 0; it < NT - 1; ++it) {
        // ===== phase D(it): dissipation at (ed[it], -d_it) =====
        // tD already holds volley(A1[1], XD(it)) from the previous phase.
        bar_lds();                               // syncs dredE writes
        F4 dp; dp.v = dredE[s];                  // ds_read (latency hides below)
        // hoisted NEXT-phase volley: XE(it) <- e[it+1] (regs only, no barrier dep)
        XE.i[0] = g0 ? cvtpk(eR0.x, eR0.y) : 0;
        XE.i[1] = g0 ? cvtpk(eR1.x, eR1.y) : 0;
        XE.i[2] = g0 ? cvtpk(eR2.x, eR2.y) : 0;
        XE.i[3] = g0 ? K67 : 0;
        volley(A1[0], XE.v, tE);                 // runs in ds_read shadow
        const float d = (dp.f[0] + dp.f[1]) + (dp.f[2] + dp.f[3]);
        corr8(tD, w6r[1], d);                    // w6r[1] pre-negated => -d
        accD.v = packL2(A2[1], tD);
        F4 sp; sp.v = accE.v - accD.v;           // stress[it] partial
        if (lane < 32) redS[w][lane].v = sp.v;
        if (g == 1) ((float*)&dredD[s])[w] = accD.f[2];   // kin partial
        // off-chain: issue load e[it+2]
        {
            const int tn = (it + 2 < NT) ? it + 2 : NT - 1;
            eR0 = pE[3 * tn]; eR1 = pE[3 * tn + 1]; eR2 = pE[3 * tn + 2];
        }

        // ===== phase E(it): energy at (e[it+1], xi_{it+1}) =====
        // tE already holds volley(A1[0], XE(it)).
        bar_lds();                               // syncs dredD + redS writes
        F4 dq; dq.v = dredD[s];
        // hoisted NEXT-phase volley: XD(it+1) <- ed[it+1]
        XD.i[0] = g0 ? cvtpk(dR0.x, dR0.y) : 0;
        XD.i[1] = g0 ? cvtpk(dR1.x, dR1.y) : 0;
        XD.i[2] = g0 ? cvtpk(dR2.x, dR2.y) : 0;
        XD.i[3] = g0 ? K67 : 0;
        volley(A1[1], XD.v, tD);                 // runs in ds_read shadow
        // lazy stress sum + store; alternate waves 2/3 to halve barrier skew
        // (reads drain before that wave's next bar_lds -> race-free as visco10)
        if (w == 2 + (it & 1)) {
            const int l31 = lane & 31;
            f4v st = (redS[0][l31].v + redS[1][l31].v) +
                     (redS[2][l31].v + redS[3][l31].v);
            float* ps = sB + it * 6;
            if (g == 0) {
                ((f2v*)ps)[0] = f2v{st.x, st.y};
                ((f2v*)ps)[1] = f2v{st.z, st.w};
            } else if (g == 1) {
                ((f2v*)ps)[2] = f2v{st.x, st.y};
            }
        }
        const float kin = (dq.f[0] + dq.f[1]) + (dq.f[2] + dq.f[3]);
        xi = fmaf(DTC, kin, xi);
        if (w == 1 && g0) xB[it + 1] = xi;
        corr8(tE, w6r[0], xi);
        accE.v = packL2(A2[0], tE);
        if (g == 1) ((float*)&dredE[s])[w] = accE.f[2];
        // off-chain: issue load ed[it+2]
        {
            const int tn = (it + 2 < NT) ? it + 2 : NT - 1;
            dR0 = pD[3 * tn]; dR1 = pD[3 * tn + 1]; dR2 = pD[3 * tn + 2];
        }
    }

    // ===== epilogue: stress[127] = s_eq(final E) - s_neq(final D) =====
    bar_lds();   // all waves' in-flight redS reads drained (own lgkm drain)
    F4 spf; spf.v = accE.v - accD.v;
    if (lane < 32) redS[w][lane].v = spf.v;
    bar_lds();
    if (w == 3) {
        const int l31 = lane & 31;
        f4v st = (redS[0][l31].v + redS[1][l31].v) +
                 (redS[2][l31].v + redS[3][l31].v);
        float* ps = sB + (NT - 1) * 6;
        if (g == 0) {
            ((f2v*)ps)[0] = f2v{st.x, st.y};
            ((f2v*)ps)[1] = f2v{st.z, st.w};
        } else if (g == 1) {
            ((f2v*)ps)[2] = f2v{st.x, st.y};
        }
    }
}

extern "C" void kernel_launch(void* const* d_in, const int* in_sizes, int n_in,
                              void* d_out, int out_size, void* d_ws, size_t ws_size,
                              hipStream_t stream) {
    const float* e    = (const float*)d_in[0];
    const float* edot = (const float*)d_in[1];
    const float* We1  = (const float*)d_in[2];
    const float* be1  = (const float*)d_in[3];
    const float* we2  = (const float*)d_in[4];
    // d_in[5] = be2 (constant, vanishes in gradient)
    const float* Wd1  = (const float*)d_in[6];
    const float* bd1  = (const float*)d_in[7];
    const float* wd2  = (const float*)d_in[8];
    // d_in[9] = bd2 (unused)

    float* out_stress = (float*)d_out;                         // [B,T,6]
    float* out_xi     = (float*)d_out + (size_t)NB * NT * 6;   // [B,T,1]

    visco15<<<NB / 16, 256, 0, stream>>>(e, edot, We1, be1, we2,
                                         Wd1, bd1, wd2, out_stress, out_xi);
}